// Round 4
// baseline (258.888 us; speedup 1.0000x reference)
//
#include <hip/hip_runtime.h>
#include <math.h>

// Problem constants (match reference: D=256, HID=512, N=100000)
#define DDIM   256
#define HID    512
#define SBLK   512   // number of stm partial blocks (also ltm)
#define TR     32    // tile rows staged per double-buffer slot (32 KB)

// Workspace layout (float offsets)
#define OFF_M     0
#define OFF_L     (SBLK)
#define OFF_SACC  (2*SBLK)
#define OFF_LACC  (OFF_SACC + SBLK*DDIM)
#define OFF_FUSED (OFF_LACC + SBLK*DDIM)
#define OFF_H     (OFF_FUSED + 3*DDIM)
// total floats = 2*512 + 2*512*256 + 768 + 512 = 264448  (~1.01 MB)

#define GLOBAL_AS __attribute__((address_space(1)))
#define LDS_AS    __attribute__((address_space(3)))

// Async global->LDS DMA, 16 B/lane: lane i's 16 B land at ldsbase + 16*i.
// ldsbase must be wave-uniform; gsrc is per-lane.
__device__ __forceinline__ void lds_dma16(const float* gsrc, float* ldsbase) {
    __builtin_amdgcn_global_load_lds((const GLOBAL_AS void*)gsrc,
                                     (LDS_AS void*)ldsbase, 16, 0, 0);
}

// ---------------------------------------------------------------------------
// Kernel A: blocks [0,512): stm online-softmax partials; [512,1024): ltm sums.
// 256 threads = 4 waves. Per tile of 32 rows: all waves issue global_load_lds
// dwordx4 DMA for tile t+1 (8 rows/wave), then compute tile t from LDS.
// __syncthreads() drains vmcnt before the barrier (m97 semantics), so the
// next tile is complete when the loop advances. In-flight per CU during the
// drain: 2 blocks x 32 KB = 64 KB >> the ~9 KB needed for full stream rate.
// ---------------------------------------------------------------------------
__global__ __launch_bounds__(256) void kA(const float* __restrict__ x_t,
                                          const float* __restrict__ stm_emb,
                                          const float* __restrict__ stm_w,
                                          const float* __restrict__ ltm_emb,
                                          const float* __restrict__ ltm_w,
                                          float* __restrict__ ws, int N)
{
    const int t    = threadIdx.x;
    const int lane = t & 63;
    const int wave = t >> 6;          // 4 waves

    __shared__ float buf[2][TR * DDIM];   // 2 x 32 KB staging buffers
    __shared__ float wsl[256];            // per-block weight slice (0 past re)
    __shared__ float s_acc[4][DDIM];      // 4 KB merge scratch
    __shared__ float s_m[4];
    __shared__ float s_l[4];

    const int  bid    = blockIdx.x;
    const bool is_stm = bid < SBLK;
    const int  b      = is_stm ? bid : bid - SBLK;
    const float* emb  = is_stm ? stm_emb : ltm_emb;
    const float* wgt  = is_stm ? stm_w   : ltm_w;

    const int rs  = (int)(((long long)b     * N) / SBLK);
    const int re  = (int)(((long long)(b+1) * N) / SBLK);
    const int cnt = re - rs;                       // 195 or 196 (<256)
    const int nt  = (cnt + TR - 1) / TR;

    // weight slice -> LDS, zeroed past re so fake rows contribute 0 (ltm)
    wsl[t] = ((rs + t < re) && (t < 256)) ? wgt[rs + t] : 0.f;

    const float4 x4 = reinterpret_cast<const float4*>(x_t)[lane];

    // ---- stage tile ti into buf[bsel]: 8 rows per wave, 1 KB DMA per row
    auto stage = [&](int ti, int bsel) {
        const int t0 = rs + ti * TR;
        #pragma unroll
        for (int k = 0; k < 8; ++k) {
            const int j   = wave * 8 + k;
            int row = t0 + j;
            row = (row < N) ? row : (N - 1);       // clamp: valid addr, masked later
            lds_dma16(emb + (size_t)row * DDIM + lane * 4, &buf[bsel][j * DDIM]);
        }
    };

    float m = -1e30f, l = 0.f;
    float ax = 0.f, ay = 0.f, az = 0.f, aw = 0.f;

    stage(0, 0);
    __syncthreads();   // drains DMA (vmcnt) + makes wsl visible

    for (int ti = 0; ti < nt; ++ti) {
        const int bs = ti & 1;
        if (ti + 1 < nt) stage(ti + 1, bs ^ 1);

        const float* bp = buf[bs];
        const int    t0 = rs + ti * TR;

        if (is_stm) {
            #pragma unroll
            for (int k = 0; k < 8; ++k) {
                const int j   = wave * 8 + k;
                const int row = t0 + j;
                float4 e  = reinterpret_cast<const float4*>(bp + j * DDIM)[lane];
                float  wv = wsl[ti * TR + j];      // broadcast ds_read
                float  p  = e.x*x4.x + e.y*x4.y + e.z*x4.z + e.w*x4.w;
                #pragma unroll
                for (int off = 32; off > 0; off >>= 1)
                    p += __shfl_xor(p, off, 64);   // bit-identical across lanes
                float s  = (row < re) ? p * wv : -1e30f;
                float mn = fmaxf(m, s);
                float sc = __expf(m - mn);
                float q  = __expf(s - mn);
                m  = mn;
                l  = l*sc + q;
                ax = ax*sc + q*e.x; ay = ay*sc + q*e.y;
                az = az*sc + q*e.z; aw = aw*sc + q*e.w;
            }
        } else {
            #pragma unroll
            for (int k = 0; k < 8; ++k) {
                const int j  = wave * 8 + k;
                float4 e  = reinterpret_cast<const float4*>(bp + j * DDIM)[lane];
                float  wv = wsl[ti * TR + j];      // 0 for rows >= re
                ax += wv * e.x; ay += wv * e.y;
                az += wv * e.z; aw += wv * e.w;
            }
        }
        __syncthreads();   // tile ti+1 DMA drained; buf[bs] free for ti+2
    }

    // ---- block-level merge across the 4 waves ----
    reinterpret_cast<float4*>(s_acc[wave])[lane] = make_float4(ax, ay, az, aw);
    if (lane == 0) { s_m[wave] = m; s_l[wave] = l; }
    __syncthreads();

    if (is_stm) {
        float M = fmaxf(fmaxf(s_m[0], s_m[1]), fmaxf(s_m[2], s_m[3]));
        float e0 = __expf(s_m[0] - M), e1 = __expf(s_m[1] - M);
        float e2 = __expf(s_m[2] - M), e3 = __expf(s_m[3] - M);
        float L  = s_l[0]*e0 + s_l[1]*e1 + s_l[2]*e2 + s_l[3]*e3;
        float av = s_acc[0][t]*e0 + s_acc[1][t]*e1 + s_acc[2][t]*e2 + s_acc[3][t]*e3;
        ws[OFF_SACC + b*DDIM + t] = av;
        if (t == 0) { ws[OFF_M + b] = M; ws[OFF_L + b] = L; }
    } else {
        float av = s_acc[0][t] + s_acc[1][t] + s_acc[2][t] + s_acc[3][t];
        ws[OFF_LACC + b*DDIM + t] = av;
    }
}

// ---------------------------------------------------------------------------
// Kernel B: merge the 512 softmax partials + 512 ltm partials -> fused[768].
// grid=8 blocks; each block redundantly computes global (M,L) and an LDS
// table of per-block scales sc[b]=exp(m_b-M), then owns 32 d-columns.
// Block 0 also copies x_t into fused, inits h=b1 and out=b2.
// ---------------------------------------------------------------------------
__global__ __launch_bounds__(256) void kB(const float* __restrict__ x_t,
                                          const float* __restrict__ b1,
                                          const float* __restrict__ b2,
                                          float* __restrict__ ws,
                                          float* __restrict__ out)
{
    __shared__ float red[256];
    __shared__ float scl[SBLK];
    __shared__ float r1[256];
    __shared__ float r2[256];
    const int t = threadIdx.x;

    const float* ws_m = ws + OFF_M;
    const float* ws_l = ws + OFF_L;
    const float* sacc = ws + OFF_SACC;
    const float* lacc = ws + OFF_LACC;
    float* fused = ws + OFF_FUSED;
    float* hbuf  = ws + OFF_H;

    // global max M over 512 block maxima
    float m0 = ws_m[t], m1 = ws_m[t + 256];
    red[t] = fmaxf(m0, m1); __syncthreads();
    for (int s = 128; s > 0; s >>= 1) {
        if (t < s) red[t] = fmaxf(red[t], red[t + s]);
        __syncthreads();
    }
    const float M = red[0];
    __syncthreads();

    // per-partial scales into LDS, then global denominator L
    float sc0 = __expf(m0 - M), sc1 = __expf(m1 - M);
    scl[t] = sc0; scl[t + 256] = sc1;
    red[t] = ws_l[t] * sc0 + ws_l[t + 256] * sc1;
    __syncthreads();
    for (int s = 128; s > 0; s >>= 1) {
        if (t < s) red[t] += red[t + s];
        __syncthreads();
    }
    const float L = red[0];
    __syncthreads();

    // this block owns d in [d0, d0+32)
    const int ell = t & 31;
    const int g   = t >> 5;          // 8 groups of 32 lanes
    const int d0  = blockIdx.x * 32;

    float sa = 0.f, la = 0.f;
    #pragma unroll 4
    for (int b = g; b < SBLK; b += 8) {
        sa += sacc[b*DDIM + d0 + ell] * scl[b];
        la += lacc[b*DDIM + d0 + ell];
    }
    r1[t] = sa; r2[t] = la;
    __syncthreads();
    if (g == 0) {
        float S = 0.f, Qs = 0.f;
        #pragma unroll
        for (int gg = 0; gg < 8; gg++) { S += r1[gg*32 + ell]; Qs += r2[gg*32 + ell]; }
        fused[DDIM   + d0 + ell] = S / L;   // r_s
        fused[2*DDIM + d0 + ell] = Qs;      // r_l
    }

    if (blockIdx.x == 0) {
        fused[t] = x_t[t];                  // x part of fused
        hbuf[t]        = b1[t];             // init h with bias (atomics add later)
        hbuf[t + 256]  = b1[t + 256];
        out[t]         = b2[t];             // init out with bias
    }
}

// ---------------------------------------------------------------------------
// Kernel C: h += fused @ w1 over a k-chunk of 64. grid = 12 kchunks x 2 halves.
// ---------------------------------------------------------------------------
__global__ __launch_bounds__(256) void kC(const float* __restrict__ w1,
                                          float* __restrict__ ws)
{
    __shared__ float fl[64];
    const int t     = threadIdx.x;
    const int k0    = (blockIdx.x >> 1) * 64;
    const int h_idx = (blockIdx.x & 1) * 256 + t;
    const float* fused = ws + OFF_FUSED;
    float* hbuf = ws + OFF_H;

    if (t < 64) fl[t] = fused[k0 + t];
    __syncthreads();

    float acc = 0.f;
    #pragma unroll 16
    for (int k = 0; k < 64; k++)
        acc += fl[k] * w1[(k0 + k) * HID + h_idx];   // coalesced over h_idx
    atomicAdd(&hbuf[h_idx], acc);
}

// ---------------------------------------------------------------------------
// Kernel D: out += relu(h) @ w2 over a k-chunk of 64. grid = 8 kchunks.
// ---------------------------------------------------------------------------
__global__ __launch_bounds__(256) void kD(const float* __restrict__ w2,
                                          const float* __restrict__ ws,
                                          float* __restrict__ out)
{
    __shared__ float hl[64];
    const int t  = threadIdx.x;
    const int k0 = blockIdx.x * 64;
    const float* hbuf = ws + OFF_H;

    if (t < 64) hl[t] = fmaxf(hbuf[k0 + t], 0.f);
    __syncthreads();

    float acc = 0.f;
    #pragma unroll 16
    for (int k = 0; k < 64; k++)
        acc += hl[k] * w2[(k0 + k) * DDIM + t];      // coalesced over t
    atomicAdd(&out[t], acc);
}

extern "C" void kernel_launch(void* const* d_in, const int* in_sizes, int n_in,
                              void* d_out, int out_size, void* d_ws, size_t ws_size,
                              hipStream_t stream)
{
    const float* x_t     = (const float*)d_in[0];
    const float* stm_emb = (const float*)d_in[1];
    const float* stm_w   = (const float*)d_in[2];
    const float* ltm_emb = (const float*)d_in[3];
    const float* ltm_w   = (const float*)d_in[4];
    const float* w1      = (const float*)d_in[5];
    const float* b1      = (const float*)d_in[6];
    const float* w2      = (const float*)d_in[7];
    const float* b2      = (const float*)d_in[8];
    float* out = (float*)d_out;
    float* ws  = (float*)d_ws;
    const int N = in_sizes[2];   // 100000

    kA<<<2 * SBLK, 256, 0, stream>>>(x_t, stm_emb, stm_w, ltm_emb, ltm_w, ws, N);
    kB<<<8,        256, 0, stream>>>(x_t, b1, b2, ws, out);
    kC<<<24,       256, 0, stream>>>(w1, ws);
    kD<<<8,        256, 0, stream>>>(w2, ws, out);
}

// Round 5
// 230.398 us; speedup vs baseline: 1.1237x; 1.1237x over previous
//
#include <hip/hip_runtime.h>
#include <math.h>

// Problem constants (match reference: D=256, HID=512, N=100000)
#define DDIM   256
#define HID    512
#define SBLK   512   // number of stm partial blocks (also ltm)

// Workspace layout (float offsets)
#define OFF_M     0
#define OFF_L     (SBLK)
#define OFF_SACC  (2*SBLK)
#define OFF_LACC  (OFF_SACC + SBLK*DDIM)
#define OFF_FUSED (OFF_LACC + SBLK*DDIM)
#define OFF_H     (OFF_FUSED + 3*DDIM)
// total floats = 2*512 + 2*512*256 + 768 + 512 = 264448  (~1.01 MB)

typedef float v4f __attribute__((ext_vector_type(4)));

// Non-temporal 16B load: global_load_dwordx4 ... nt — no L2/L3 allocation on
// miss (read-once stream), still hits if the line is already resident.
__device__ __forceinline__ v4f nt_load4(const v4f* p) {
    return __builtin_nontemporal_load(p);
}

// ---------------------------------------------------------------------------
// Kernel A: blocks [0,512): stm online-softmax partials; [512,1024): ltm sums.
// 256 threads = 4 waves; 1024 blocks -> exactly 4 blocks/CU, 16 waves/CU
// (VGPR cap 128 via __launch_bounds__(256,4) so the depth-1 quad prefetch
// REALLY lives in registers this time — verify VGPR_Count >= ~96).
// Each wave streams contiguous row-quads (4 rows, 4 KB) with the next quad's
// 4 embedding float4s + weight float4 issued before the current quad's
// reduce/exp/accumulate chain. All bulk loads are non-temporal so kA does not
// evict the harness-restore's dirty L3 lines (writeback-storm avoidance).
// ---------------------------------------------------------------------------
__global__ __launch_bounds__(256, 4) void kA(const float* __restrict__ x_t,
                                             const float* __restrict__ stm_emb,
                                             const float* __restrict__ stm_w,
                                             const float* __restrict__ ltm_emb,
                                             const float* __restrict__ ltm_w,
                                             float* __restrict__ ws, int N)
{
    const int t    = threadIdx.x;
    const int lane = t & 63;
    const int wave = t >> 6;          // 4 waves

    __shared__ float s_acc[4][DDIM];  // 4 KB merge scratch
    __shared__ float s_m[4];
    __shared__ float s_l[4];

    const v4f x4 = reinterpret_cast<const v4f*>(x_t)[lane];
    const int Q   = N >> 2;           // full row-quads (25000 for N=100000)
    const int bid = blockIdx.x;

    if (bid < SBLK) {
        // ---- STM: fused online-softmax + weighted accumulate ----
        const int b  = bid;
        const int qs = (int)(((long long)b     * Q) / SBLK);
        const int qe = (int)(((long long)(b+1) * Q) / SBLK);
        const v4f* emb4 = reinterpret_cast<const v4f*>(stm_emb);
        const v4f* w4   = reinterpret_cast<const v4f*>(stm_w);

        float m = -1e30f, l = 0.f;
        float ax = 0.f, ay = 0.f, az = 0.f, aw = 0.f;

        int q = qs + wave;
        if (q < qe) {
            size_t base = (size_t)q * 256 + lane;       // v4f index of row 4q
            v4f E0 = nt_load4(emb4 + base      );
            v4f E1 = nt_load4(emb4 + base +  64);
            v4f E2 = nt_load4(emb4 + base + 128);
            v4f E3 = nt_load4(emb4 + base + 192);
            v4f W  = nt_load4(w4 + q);
            while (true) {
                const int  qn   = q + 4;
                const bool more = qn < qe;
                const int  qp   = more ? qn : q;        // clamp: cache-hit reload
                size_t pb = (size_t)qp * 256 + lane;
                v4f F0 = nt_load4(emb4 + pb      );     // prefetch issued FIRST
                v4f F1 = nt_load4(emb4 + pb +  64);
                v4f F2 = nt_load4(emb4 + pb + 128);
                v4f F3 = nt_load4(emb4 + pb + 192);
                v4f Wn = nt_load4(w4 + qp);

                float p0 = E0.x*x4.x + E0.y*x4.y + E0.z*x4.z + E0.w*x4.w;
                float p1 = E1.x*x4.x + E1.y*x4.y + E1.z*x4.z + E1.w*x4.w;
                float p2 = E2.x*x4.x + E2.y*x4.y + E2.z*x4.z + E2.w*x4.w;
                float p3 = E3.x*x4.x + E3.y*x4.y + E3.z*x4.z + E3.w*x4.w;
                #pragma unroll
                for (int off = 32; off > 0; off >>= 1) { // 4 independent chains
                    p0 += __shfl_xor(p0, off, 64);
                    p1 += __shfl_xor(p1, off, 64);
                    p2 += __shfl_xor(p2, off, 64);
                    p3 += __shfl_xor(p3, off, 64);
                }
                float s0 = p0 * W.x, s1 = p1 * W.y;
                float s2 = p2 * W.z, s3 = p3 * W.w;

                float smax = fmaxf(fmaxf(s0, s1), fmaxf(s2, s3));
                float mn   = fmaxf(m, smax);
                float sc   = __expf(m - mn);
                float q0 = __expf(s0 - mn), q1 = __expf(s1 - mn);
                float q2 = __expf(s2 - mn), q3 = __expf(s3 - mn);
                m = mn;
                l  = l*sc + ((q0 + q1) + (q2 + q3));
                ax = ax*sc + (q0*E0.x + q1*E1.x) + (q2*E2.x + q3*E3.x);
                ay = ay*sc + (q0*E0.y + q1*E1.y) + (q2*E2.y + q3*E3.y);
                az = az*sc + (q0*E0.z + q1*E1.z) + (q2*E2.z + q3*E3.z);
                aw = aw*sc + (q0*E0.w + q1*E1.w) + (q2*E2.w + q3*E3.w);

                if (!more) break;
                E0 = F0; E1 = F1; E2 = F2; E3 = F3; W = Wn; q = qn;
            }
        }
        // tail rows (N & 3, zero for N=100000) handled by last stm block
        if (b == SBLK - 1) {
            const int tail = N & 3;
            const int r    = (Q << 2) + wave;
            if (wave < tail) {
                v4f e = reinterpret_cast<const v4f*>(stm_emb)[(size_t)r * 64 + lane];
                float wv = stm_w[r];
                float p = e.x*x4.x + e.y*x4.y + e.z*x4.z + e.w*x4.w;
                #pragma unroll
                for (int off = 32; off > 0; off >>= 1)
                    p += __shfl_xor(p, off, 64);
                float s  = p * wv;
                float mn = fmaxf(m, s);
                float sc = __expf(m - mn);
                float qq = __expf(s - mn);
                m = mn;
                l  = l*sc + qq;
                ax = ax*sc + qq*e.x; ay = ay*sc + qq*e.y;
                az = az*sc + qq*e.z; aw = aw*sc + qq*e.w;
            }
        }

        s_acc[wave][lane*4+0] = ax;
        s_acc[wave][lane*4+1] = ay;
        s_acc[wave][lane*4+2] = az;
        s_acc[wave][lane*4+3] = aw;
        if (lane == 0) { s_m[wave] = m; s_l[wave] = l; }
        __syncthreads();

        float M  = fmaxf(fmaxf(s_m[0], s_m[1]), fmaxf(s_m[2], s_m[3]));
        float e0 = __expf(s_m[0] - M), e1 = __expf(s_m[1] - M);
        float e2 = __expf(s_m[2] - M), e3 = __expf(s_m[3] - M);
        float L  = s_l[0]*e0 + s_l[1]*e1 + s_l[2]*e2 + s_l[3]*e3;
        float av = s_acc[0][t]*e0 + s_acc[1][t]*e1 + s_acc[2][t]*e2 + s_acc[3][t]*e3;
        ws[OFF_SACC + b*DDIM + t] = av;
        if (t == 0) { ws[OFF_M + b] = M; ws[OFF_L + b] = L; }
    } else {
        // ---- LTM: plain weighted sum, same pipelined NT stream ----
        const int b  = bid - SBLK;
        const int qs = (int)(((long long)b     * Q) / SBLK);
        const int qe = (int)(((long long)(b+1) * Q) / SBLK);
        const v4f* emb4 = reinterpret_cast<const v4f*>(ltm_emb);
        const v4f* w4   = reinterpret_cast<const v4f*>(ltm_w);

        float ax = 0.f, ay = 0.f, az = 0.f, aw = 0.f;
        int q = qs + wave;
        if (q < qe) {
            size_t base = (size_t)q * 256 + lane;
            v4f E0 = nt_load4(emb4 + base      );
            v4f E1 = nt_load4(emb4 + base +  64);
            v4f E2 = nt_load4(emb4 + base + 128);
            v4f E3 = nt_load4(emb4 + base + 192);
            v4f W  = nt_load4(w4 + q);
            while (true) {
                const int  qn   = q + 4;
                const bool more = qn < qe;
                const int  qp   = more ? qn : q;
                size_t pb = (size_t)qp * 256 + lane;
                v4f F0 = nt_load4(emb4 + pb      );
                v4f F1 = nt_load4(emb4 + pb +  64);
                v4f F2 = nt_load4(emb4 + pb + 128);
                v4f F3 = nt_load4(emb4 + pb + 192);
                v4f Wn = nt_load4(w4 + qp);

                ax += (W.x*E0.x + W.y*E1.x) + (W.z*E2.x + W.w*E3.x);
                ay += (W.x*E0.y + W.y*E1.y) + (W.z*E2.y + W.w*E3.y);
                az += (W.x*E0.z + W.y*E1.z) + (W.z*E2.z + W.w*E3.z);
                aw += (W.x*E0.w + W.y*E1.w) + (W.z*E2.w + W.w*E3.w);

                if (!more) break;
                E0 = F0; E1 = F1; E2 = F2; E3 = F3; W = Wn; q = qn;
            }
        }
        if (b == SBLK - 1) {
            const int tail = N & 3;
            const int r    = (Q << 2) + wave;
            if (wave < tail) {
                v4f e = reinterpret_cast<const v4f*>(ltm_emb)[(size_t)r * 64 + lane];
                float wv = ltm_w[r];
                ax += wv*e.x; ay += wv*e.y; az += wv*e.z; aw += wv*e.w;
            }
        }

        s_acc[wave][lane*4+0] = ax;
        s_acc[wave][lane*4+1] = ay;
        s_acc[wave][lane*4+2] = az;
        s_acc[wave][lane*4+3] = aw;
        __syncthreads();
        float av = s_acc[0][t] + s_acc[1][t] + s_acc[2][t] + s_acc[3][t];
        ws[OFF_LACC + b*DDIM + t] = av;
    }
}

// ---------------------------------------------------------------------------
// Kernel B: merge the 512 softmax partials + 512 ltm partials -> fused[768].
// grid=8 blocks; each block redundantly computes global (M,L) and an LDS
// table of per-block scales sc[b]=exp(m_b-M), then owns 32 d-columns.
// Block 0 also copies x_t into fused, inits h=b1 and out=b2.
// ---------------------------------------------------------------------------
__global__ __launch_bounds__(256) void kB(const float* __restrict__ x_t,
                                          const float* __restrict__ b1,
                                          const float* __restrict__ b2,
                                          float* __restrict__ ws,
                                          float* __restrict__ out)
{
    __shared__ float red[256];
    __shared__ float scl[SBLK];
    __shared__ float r1[256];
    __shared__ float r2[256];
    const int t = threadIdx.x;

    const float* ws_m = ws + OFF_M;
    const float* ws_l = ws + OFF_L;
    const float* sacc = ws + OFF_SACC;
    const float* lacc = ws + OFF_LACC;
    float* fused = ws + OFF_FUSED;
    float* hbuf  = ws + OFF_H;

    // global max M over 512 block maxima
    float m0 = ws_m[t], m1 = ws_m[t + 256];
    red[t] = fmaxf(m0, m1); __syncthreads();
    for (int s = 128; s > 0; s >>= 1) {
        if (t < s) red[t] = fmaxf(red[t], red[t + s]);
        __syncthreads();
    }
    const float M = red[0];
    __syncthreads();

    // per-partial scales into LDS, then global denominator L
    float sc0 = __expf(m0 - M), sc1 = __expf(m1 - M);
    scl[t] = sc0; scl[t + 256] = sc1;
    red[t] = ws_l[t] * sc0 + ws_l[t + 256] * sc1;
    __syncthreads();
    for (int s = 128; s > 0; s >>= 1) {
        if (t < s) red[t] += red[t + s];
        __syncthreads();
    }
    const float L = red[0];
    __syncthreads();

    // this block owns d in [d0, d0+32)
    const int ell = t & 31;
    const int g   = t >> 5;          // 8 groups of 32 lanes
    const int d0  = blockIdx.x * 32;

    float sa = 0.f, la = 0.f;
    #pragma unroll 4
    for (int b = g; b < SBLK; b += 8) {
        sa += sacc[b*DDIM + d0 + ell] * scl[b];
        la += lacc[b*DDIM + d0 + ell];
    }
    r1[t] = sa; r2[t] = la;
    __syncthreads();
    if (g == 0) {
        float S = 0.f, Qs = 0.f;
        #pragma unroll
        for (int gg = 0; gg < 8; gg++) { S += r1[gg*32 + ell]; Qs += r2[gg*32 + ell]; }
        fused[DDIM   + d0 + ell] = S / L;   // r_s
        fused[2*DDIM + d0 + ell] = Qs;      // r_l
    }

    if (blockIdx.x == 0) {
        fused[t] = x_t[t];                  // x part of fused
        hbuf[t]        = b1[t];             // init h with bias (atomics add later)
        hbuf[t + 256]  = b1[t + 256];
        out[t]         = b2[t];             // init out with bias
    }
}

// ---------------------------------------------------------------------------
// Kernel C: h += fused @ w1 over a k-chunk of 64. grid = 12 kchunks x 2 halves.
// ---------------------------------------------------------------------------
__global__ __launch_bounds__(256) void kC(const float* __restrict__ w1,
                                          float* __restrict__ ws)
{
    __shared__ float fl[64];
    const int t     = threadIdx.x;
    const int k0    = (blockIdx.x >> 1) * 64;
    const int h_idx = (blockIdx.x & 1) * 256 + t;
    const float* fused = ws + OFF_FUSED;
    float* hbuf = ws + OFF_H;

    if (t < 64) fl[t] = fused[k0 + t];
    __syncthreads();

    float acc = 0.f;
    #pragma unroll 16
    for (int k = 0; k < 64; k++)
        acc += fl[k] * w1[(k0 + k) * HID + h_idx];   // coalesced over h_idx
    atomicAdd(&hbuf[h_idx], acc);
}

// ---------------------------------------------------------------------------
// Kernel D: out += relu(h) @ w2 over a k-chunk of 64. grid = 8 kchunks.
// ---------------------------------------------------------------------------
__global__ __launch_bounds__(256) void kD(const float* __restrict__ w2,
                                          const float* __restrict__ ws,
                                          float* __restrict__ out)
{
    __shared__ float hl[64];
    const int t  = threadIdx.x;
    const int k0 = blockIdx.x * 64;
    const float* hbuf = ws + OFF_H;

    if (t < 64) hl[t] = fmaxf(hbuf[k0 + t], 0.f);
    __syncthreads();

    float acc = 0.f;
    #pragma unroll 16
    for (int k = 0; k < 64; k++)
        acc += hl[k] * w2[(k0 + k) * DDIM + t];      // coalesced over t
    atomicAdd(&out[t], acc);
}

extern "C" void kernel_launch(void* const* d_in, const int* in_sizes, int n_in,
                              void* d_out, int out_size, void* d_ws, size_t ws_size,
                              hipStream_t stream)
{
    const float* x_t     = (const float*)d_in[0];
    const float* stm_emb = (const float*)d_in[1];
    const float* stm_w   = (const float*)d_in[2];
    const float* ltm_emb = (const float*)d_in[3];
    const float* ltm_w   = (const float*)d_in[4];
    const float* w1      = (const float*)d_in[5];
    const float* b1      = (const float*)d_in[6];
    const float* w2      = (const float*)d_in[7];
    const float* b2      = (const float*)d_in[8];
    float* out = (float*)d_out;
    float* ws  = (float*)d_ws;
    const int N = in_sizes[2];   // 100000

    kA<<<2 * SBLK, 256, 0, stream>>>(x_t, stm_emb, stm_w, ltm_emb, ltm_w, ws, N);
    kB<<<8,        256, 0, stream>>>(x_t, b1, b2, ws, out);
    kC<<<24,       256, 0, stream>>>(w1, ws);
    kD<<<8,        256, 0, stream>>>(w2, ws, out);
}